// Round 7
// baseline (202.428 us; speedup 1.0000x reference)
//
#include <hip/hip_runtime.h>

typedef float f4v __attribute__((ext_vector_type(4)));

#define BIGV 1e10f
#define LOG2E 1.44269504f
#define LN2 0.69314718f

// softmin in log2-scaled domain (values pre-scaled by log2e): exact correspondence.
__device__ __forceinline__ float softmin3b(float a, float b, float c) {
  float m, d, M;
  asm("v_min3_f32 %0, %1, %2, %3" : "=v"(m) : "v"(a), "v"(b), "v"(c));
  asm("v_max3_f32 %0, %1, %2, %3" : "=v"(M) : "v"(a), "v"(b), "v"(c));
  asm("v_med3_f32 %0, %1, %2, %3" : "=v"(d) : "v"(a), "v"(b), "v"(c));
  float s = 1.0f + __builtin_amdgcn_exp2f(m - d) + __builtin_amdgcn_exp2f(m - M);
  return m - __log2f(s);
}

__device__ __forceinline__ float sumsq_fp8x4(unsigned int pk) {
  float d0 = __builtin_amdgcn_cvt_f32_fp8((int)pk, 0);
  float d1 = __builtin_amdgcn_cvt_f32_fp8((int)pk, 1);
  float d2 = __builtin_amdgcn_cvt_f32_fp8((int)pk, 2);
  float d3 = __builtin_amdgcn_cvt_f32_fp8((int)pk, 3);
  return (d0 * d0 + d1 * d1) + (d2 * d2 + d3 * d3);
}

// One wave per problem. fp8 MFMA cost tiles (key order K = Rt+Ct) feed a consumer-indexed
// 8-slot LDS ring; DP consumes 4x4 register tiles per wave-step (chain depth 7 per 16 cells).
__global__ __launch_bounds__(64)
void sdtw_fused2(const float* __restrict__ X, const float* __restrict__ Y,
                 float* __restrict__ out) {
  const int p = blockIdx.x;
  const int type = p >> 9;            // 0: xy, 1: xx, 2: yy
  const int b = p & 511;
  const float* Ap = (type == 2 ? Y : X) + (size_t)b * 256 * 64;
  const float* Bp = (type == 1 ? X : Y) + (size_t)b * 256 * 64;
  const float wgt = (type == 0) ? (LN2 / 512.0f) : (-LN2 / 1024.0f);

  __shared__ unsigned int sB[4096];    // fp8 B rows, swizzled: row*16 + (q ^ ((row&7)<<1))
  __shared__ unsigned int ring[2048];  // [slot 0..7][thread 0..63][cc 0..3] fp8x4 (rows 0..3)
  __shared__ float saa[256];           // 0.5*log2e*||q(A_r)||^2
  __shared__ float sbb[256];           // 0.5*log2e*||q(B_r)||^2

  const int t = threadIdx.x;
  const int hk = t >> 4, lr = t & 15;
  const int bpaddr = ((t + 63) & 63) << 2;   // bpermute byte addr of lane t-1 (lane0 wraps, overridden)

  // ---- stage B: coalesced float4 loads -> fp8 -> swizzled LDS; quantized row norms ----
  {
    const float4* B4 = (const float4*)Bp;
    #pragma unroll 4
    for (int it = 0; it < 64; ++it) {
      int pidx = it * 64 + t;          // float4 index 0..4095
      int row = pidx >> 4;             // = it*4 + (t>>4)
      int q = t & 15;
      float4 v = B4[pidx];
      unsigned int pk = __builtin_amdgcn_cvt_pk_fp8_f32(v.x, v.y, 0, false);
      pk = __builtin_amdgcn_cvt_pk_fp8_f32(v.z, v.w, pk, true);
      sB[row * 16 + (q ^ ((row & 7) << 1))] = pk;
      float pr = sumsq_fp8x4(pk);
      pr += __shfl_xor(pr, 1);
      pr += __shfl_xor(pr, 2);
      pr += __shfl_xor(pr, 4);
      pr += __shfl_xor(pr, 8);
      if (q == 0) sbb[row] = 0.5f * LOG2E * pr;
    }
  }

  // ---- A fragments -> fp8 registers; quantized row norms ----
  uint2 af[16][2];
  #pragma unroll
  for (int Rt = 0; Rt < 16; ++Rt) {
    float nrm = 0.f;
    #pragma unroll
    for (int kk = 0; kk < 2; ++kk) {
      const float4* src = (const float4*)(Ap + (Rt * 16 + lr) * 64 + kk * 32 + hk * 8);
      float4 x = src[0], y = src[1];
      unsigned int p0 = __builtin_amdgcn_cvt_pk_fp8_f32(x.x, x.y, 0, false);
      p0 = __builtin_amdgcn_cvt_pk_fp8_f32(x.z, x.w, p0, true);
      unsigned int p1 = __builtin_amdgcn_cvt_pk_fp8_f32(y.x, y.y, 0, false);
      p1 = __builtin_amdgcn_cvt_pk_fp8_f32(y.z, y.w, p1, true);
      af[Rt][kk].x = p0; af[Rt][kk].y = p1;
      nrm += sumsq_fp8x4(p0) + sumsq_fp8x4(p1);
    }
    nrm += __shfl_xor(nrm, 16);
    nrm += __shfl_xor(nrm, 32);
    if (hk == 0) saa[Rt * 16 + lr] = 0.5f * LOG2E * nrm;
  }

  // ---- producer: all tiles with Rt+Ct == K; one ds_write_b32 per lane per tile ----
  auto produce = [&](int K) {
    #pragma unroll
    for (int Rt = 0; Rt < 16; ++Rt) {
      int Ct = K - Rt;
      if (Ct >= 0 && Ct < 16) {        // wave-uniform branch
        int n = Ct * 16 + lr;
        int sw = n & 7;
        uint2 b0 = *(const uint2*)&sB[n * 16 + 2 * (hk ^ sw)];
        uint2 b1 = *(const uint2*)&sB[n * 16 + 2 * ((hk + 4) ^ sw)];
        f4v acc = {0.f, 0.f, 0.f, 0.f};
        acc = __builtin_amdgcn_mfma_f32_16x16x32_fp8_fp8(
                __builtin_bit_cast(long, af[Rt][0]), __builtin_bit_cast(long, b0), acc, 0, 0, 0);
        acc = __builtin_amdgcn_mfma_f32_16x16x32_fp8_fp8(
                __builtin_bit_cast(long, af[Rt][1]), __builtin_bit_cast(long, b1), acc, 0, 0, 0);
        const f4v aav = *(const f4v*)&saa[Rt * 16 + hk * 4];
        float bbv = sbb[n];
        float c0 = fmaf(-LOG2E, acc.x, aav.x + bbv);
        float c1 = fmaf(-LOG2E, acc.y, aav.y + bbv);
        float c2 = fmaf(-LOG2E, acc.z, aav.z + bbv);
        float c3 = fmaf(-LOG2E, acc.w, aav.w + bbv);
        unsigned int pk = __builtin_amdgcn_cvt_pk_fp8_f32(c0, c1, 0, false);
        pk = __builtin_amdgcn_cvt_pk_fp8_f32(c2, c3, pk, true);
        int S2 = 4 * K + hk + (lr >> 2);              // consumer step
        ring[(S2 & 7) * 256 + (4 * Rt + hk) * 4 + (lr & 3)] = pk;
      }
    }
  };

  // ---- DP state ----
  float L0 = BIGV, L1 = BIGV, L2 = BIGV, L3 = BIGV;   // right edge of my previous col-block
  float B0 = BIGV, B1 = BIGV, B2 = BIGV, B3 = BIGV;   // my bottom row (shfl'd to t+1)
  float T0 = BIGV, T1 = BIGV, T2 = BIGV, T3 = BIGV;   // neighbor's bottom row (this block)
  float dg = (t == 0) ? 0.0f : BIGV;                  // corner V[4t][4c]

  auto step = [&](int S, uint4 cw) {
    int c = S - t;
    bool act = (c >= 0) && (c < 64);
    unsigned int ww[4] = {cw.x, cw.y, cw.z, cw.w};
    float cost[4][4];
    #pragma unroll
    for (int cc = 0; cc < 4; ++cc) {
      cost[0][cc] = __builtin_amdgcn_cvt_f32_fp8((int)ww[cc], 0);
      cost[1][cc] = __builtin_amdgcn_cvt_f32_fp8((int)ww[cc], 1);
      cost[2][cc] = __builtin_amdgcn_cvt_f32_fp8((int)ww[cc], 2);
      cost[3][cc] = __builtin_amdgcn_cvt_f32_fp8((int)ww[cc], 3);
    }
    float v00 = cost[0][0] + softmin3b(L0, dg, T0);
    float v01 = cost[0][1] + softmin3b(v00, T0, T1);
    float v10 = cost[1][0] + softmin3b(L1, L0, v00);
    float v02 = cost[0][2] + softmin3b(v01, T1, T2);
    float v11 = cost[1][1] + softmin3b(v10, v00, v01);
    float v20 = cost[2][0] + softmin3b(L2, L1, v10);
    float v03 = cost[0][3] + softmin3b(v02, T2, T3);
    float v12 = cost[1][2] + softmin3b(v11, v01, v02);
    float v21 = cost[2][1] + softmin3b(v20, v10, v11);
    float v30 = cost[3][0] + softmin3b(L3, L2, v20);
    B0 = act ? v30 : B0;
    float t0n = __builtin_bit_cast(float,
        __builtin_amdgcn_ds_bpermute(bpaddr, __builtin_bit_cast(int, B0)));
    float v13 = cost[1][3] + softmin3b(v12, v02, v03);
    float v22 = cost[2][2] + softmin3b(v21, v11, v12);
    float v31 = cost[3][1] + softmin3b(v30, v20, v21);
    B1 = act ? v31 : B1;
    float t1n = __builtin_bit_cast(float,
        __builtin_amdgcn_ds_bpermute(bpaddr, __builtin_bit_cast(int, B1)));
    float v23 = cost[2][3] + softmin3b(v22, v12, v13);
    float v32 = cost[3][2] + softmin3b(v31, v21, v22);
    B2 = act ? v32 : B2;
    float t2n = __builtin_bit_cast(float,
        __builtin_amdgcn_ds_bpermute(bpaddr, __builtin_bit_cast(int, B2)));
    float v33 = cost[3][3] + softmin3b(v32, v22, v23);
    B3 = act ? v33 : B3;
    float t3n = __builtin_bit_cast(float,
        __builtin_amdgcn_ds_bpermute(bpaddr, __builtin_bit_cast(int, B3)));
    L0 = act ? v03 : L0;
    L1 = act ? v13 : L1;
    L2 = act ? v23 : L2;
    L3 = act ? v33 : L3;
    dg = T3;                                    // corner for next block = V[4t][4(c+1)]
    T0 = (t == 0) ? BIGV : t0n;
    T1 = (t == 0) ? BIGV : t1n;
    T2 = (t == 0) ? BIGV : t2n;
    T3 = (t == 0) ? BIGV : t3n;
  };

  produce(0);
  #pragma unroll 1
  for (int K = 0; K < 32; ++K) {
    // prefetch this group's 4 entries (keys <= K all produced), then produce K+1
    uint4 cw0 = *(const uint4*)&ring[((4 * K + 0) & 7) * 256 + t * 4];
    uint4 cw1 = *(const uint4*)&ring[((4 * K + 1) & 7) * 256 + t * 4];
    uint4 cw2 = *(const uint4*)&ring[((4 * K + 2) & 7) * 256 + t * 4];
    uint4 cw3 = *(const uint4*)&ring[((4 * K + 3) & 7) * 256 + t * 4];
    if (K < 31) produce(K + 1);
    step(4 * K + 0, cw0);
    step(4 * K + 1, cw1);
    step(4 * K + 2, cw2);
    if (K < 31) step(4 * K + 3, cw3);   // step 127 doesn't exist
  }

  // lane 63's v33 at step 126 = V[256][256] (log2 domain)
  if (t == 63) atomicAdd(out, wgt * B3);
}

extern "C" void kernel_launch(void* const* d_in, const int* in_sizes, int n_in,
                              void* d_out, int out_size, void* d_ws, size_t ws_size,
                              hipStream_t stream) {
  const float* X = (const float*)d_in[0];
  const float* Y = (const float*)d_in[1];
  float* out = (float*)d_out;
  hipMemsetAsync(out, 0, sizeof(float) * out_size, stream);
  sdtw_fused2<<<1536, 64, 0, stream>>>(X, Y, out);
}

// Round 8
// 167.989 us; speedup vs baseline: 1.2050x; 1.2050x over previous
//
#include <hip/hip_runtime.h>

typedef _Float16 h8 __attribute__((ext_vector_type(8)));
typedef float f4 __attribute__((ext_vector_type(4)));

#define TT 256
#define KK 64
#define LOG2E 1.44269504f
#define LN2 0.69314718f
#define RL 32      // ring lines (diagonals); live window <= 19
#define RSTR 65    // ring line stride in u32 (padded)
#define DEADD (1 << 28)

// One wave per problem: MFMA cost tiles in anti-diagonal key order feed a 32-line LDS ring.
// DP runs in exponential domain with explicit integer exponents: zero transcendentals.
// Payload per cell: m = 2^-frac(c) as fp8 (ring0), ci = floor(c) as u8 (ring1), c in log2-gamma units.
__global__ __launch_bounds__(64, 2)
void sdtw_fused3(const float* __restrict__ X, const float* __restrict__ Y,
                 float* __restrict__ out) {
  const int p = blockIdx.x;
  const int type = p >> 9;            // 0: xy, 1: xx, 2: yy
  const int b = p & 511;
  const float* Ap = (type == 2 ? Y : X) + (size_t)b * TT * KK;
  const float* Bp = (type == 1 ? X : Y) + (size_t)b * TT * KK;
  const float wgt = (type == 0) ? (LN2 / 512.0f) : (-LN2 / 1024.0f);  // log2-dom -> e-dom

  __shared__ unsigned int ring0[RL * RSTR];   // fp8x4 mantissas m for rows 4t..4t+3
  __shared__ unsigned int ring1[RL * RSTR];   // u8x4 integer costs ci
  __shared__ float saa[TT];                   // 0.5*log2e*||A_r||^2
  __shared__ float sbb[TT];                   // 0.5*log2e*||B_r||^2

  const int t = threadIdx.x;
  const int hk = t >> 4, lr = t & 15;

  // ---- zero-init ring: m=0,ci=0 -> value 2^-(ref+126): 126 binades below live scale (dead) ----
  #pragma unroll
  for (int i = 0; i < 33; ++i) {
    int idx = i * 64 + t;
    if (idx < RL * RSTR) { ring0[idx] = 0u; ring1[idx] = 0u; }
  }

  // ---- A fragments -> registers (f16) + row norms via in-register reduce ----
  h8 af[16][2];
  #pragma unroll
  for (int Rt = 0; Rt < 16; ++Rt) {
    float s = 0.f;
    #pragma unroll
    for (int kk = 0; kk < 2; ++kk) {
      const float4* src = (const float4*)(Ap + (Rt * 16 + lr) * KK + kk * 32 + hk * 8);
      float4 x = src[0], y = src[1];
      af[Rt][kk] = (h8){(_Float16)x.x, (_Float16)x.y, (_Float16)x.z, (_Float16)x.w,
                        (_Float16)y.x, (_Float16)y.y, (_Float16)y.z, (_Float16)y.w};
      s += x.x * x.x + x.y * x.y + x.z * x.z + x.w * x.w
         + y.x * y.x + y.y * y.y + y.z * y.z + y.w * y.w;
    }
    s += __shfl_xor(s, 16);
    s += __shfl_xor(s, 32);
    if (hk == (Rt & 3)) saa[Rt * 16 + lr] = 0.5f * LOG2E * s;
  }

  h8 bwin[4][2];                      // sliding B-fragment window, slot = Ct & 3

  // ---- DP state: (E, d) pairs, true value 2^-V = E * 2^-d ----
  float E1 = 0.f, E2 = 0.f, E3 = 0.f, E4 = 0.f;
  int d1 = DEADD, d2 = DEADD, d3 = DEADD, d4 = DEADD;
  float dgE = (t == 0) ? 1.0f : 0.f;  // V[4t][j-1]; lane0: V[0][0]=0 -> (1,0)
  int dgd = (t == 0) ? 0 : DEADD;

  // one DP cell, all full-rate VALU: ref-align, sum, scale by m, renorm via exponent bits
  auto cell = [&](float& vE, int& vd, float EL, int dL, float ED, int dD,
                  float EU, int dU, float m, int ci) {
    int ref = min(min(dL, dD), dU);
    float S = ldexpf(EL, ref - dL) + ldexpf(ED, ref - dD) + ldexpf(EU, ref - dU);
    float v = m * S;
    unsigned int u = __builtin_bit_cast(unsigned int, v);
    vE = __builtin_bit_cast(float, (u & 0x007FFFFFu) | 0x3F000000u);  // mantissa in [0.5,1)
    vd = ref + ci + 126 - (int)(u >> 23);
  };

  auto step = [&](unsigned int w0, unsigned int w1) {
    float upE = __shfl_up(E4, 1);     // neighbor bottom row V[4t-1][j] from prev step
    int upd = __shfl_up(d4, 1);
    if (t == 0) { upE = 0.f; upd = DEADD; }
    float m0 = __builtin_amdgcn_cvt_f32_fp8((int)w0, 0);
    float m1 = __builtin_amdgcn_cvt_f32_fp8((int)w0, 1);
    float m2 = __builtin_amdgcn_cvt_f32_fp8((int)w0, 2);
    float m3 = __builtin_amdgcn_cvt_f32_fp8((int)w0, 3);
    int ci0 = (int)(w1 & 255u), ci1 = (int)((w1 >> 8) & 255u);
    int ci2 = (int)((w1 >> 16) & 255u), ci3 = (int)(w1 >> 24);
    float v1E, v2E, v3E, v4E; int v1d, v2d, v3d, v4d;
    cell(v1E, v1d, E1, d1, dgE, dgd, upE, upd, m0, ci0);
    cell(v2E, v2d, E2, d2, E1, d1, v1E, v1d, m1, ci1);
    cell(v3E, v3d, E3, d3, E2, d2, v2E, v2d, m2, ci2);
    cell(v4E, v4d, E4, d4, E3, d3, v3E, v3d, m3, ci3);
    E1 = v1E; d1 = v1d; E2 = v2E; d2 = v2d;
    E3 = v3E; d3 = v3d; E4 = v4E; d4 = v4d;
    dgE = upE; dgd = upd;             // corner for next col = V[4t-1][j]
  };

  #pragma unroll 1
  for (int kbo = 0; kbo < 5; ++kbo) {
    #pragma unroll
    for (int q = 0; q < 4; ++q) {
      const int KB = kbo * 4 + q;     // KB = k>>2, 0..18 (KB=19 skipped)
      // ---- load B-fragment Ct=KB into slot q, norms just-in-time ----
      if (KB <= 15) {
        float s2 = 0.f;
        #pragma unroll
        for (int kk = 0; kk < 2; ++kk) {
          const float4* src = (const float4*)(Bp + (KB * 16 + lr) * KK + kk * 32 + hk * 8);
          float4 x = src[0], y = src[1];
          bwin[q][kk] = (h8){(_Float16)x.x, (_Float16)x.y, (_Float16)x.z, (_Float16)x.w,
                             (_Float16)y.x, (_Float16)y.y, (_Float16)y.z, (_Float16)y.w};
          s2 += x.x * x.x + x.y * x.y + x.z * x.z + x.w * x.w
              + y.x * y.x + y.y * y.y + y.z * y.z + y.w * y.w;
        }
        s2 += __shfl_xor(s2, 16);
        s2 += __shfl_xor(s2, 32);
        if (hk == 0) sbb[KB * 16 + lr] = 0.5f * LOG2E * s2;
      }
      if (KB <= 18) {
        #pragma unroll
        for (int r = 0; r < 4; ++r) {
          const int k = KB * 4 + r;   // tile key 4*Ct+Rt, 0..75
          // ---- produce tiles of key k: (Rt = r+4d, Ct = KB-d) ----
          #pragma unroll
          for (int dlt = 0; dlt < 4; ++dlt) {
            if (dlt <= KB && dlt >= KB - 15) {
              const int Rt = r + 4 * dlt;          // compile-time
              const int Ct = KB - dlt;
              const int slot = (q - dlt) & 3;      // compile-time
              f4 acc = {0.f, 0.f, 0.f, 0.f};
              acc = __builtin_amdgcn_mfma_f32_16x16x32_f16(af[Rt][0], bwin[slot][0], acc, 0, 0, 0);
              acc = __builtin_amdgcn_mfma_f32_16x16x32_f16(af[Rt][1], bwin[slot][1], acc, 0, 0, 0);
              const int r0 = Rt * 16 + hk * 4;
              f4 aav = *(const f4*)&saa[r0];
              float bbv = sbb[Ct * 16 + lr];
              float c0 = fminf(fmaxf(fmaf(-LOG2E, acc.x, aav.x + bbv), 0.f), 254.0f);
              float c1 = fminf(fmaxf(fmaf(-LOG2E, acc.y, aav.y + bbv), 0.f), 254.0f);
              float c2 = fminf(fmaxf(fmaf(-LOG2E, acc.z, aav.z + bbv), 0.f), 254.0f);
              float c3 = fminf(fmaxf(fmaf(-LOG2E, acc.w, aav.w + bbv), 0.f), 254.0f);
              float f0 = truncf(c0), f1 = truncf(c1), f2 = truncf(c2), f3 = truncf(c3);
              float x0 = c0 - f0, x1 = c1 - f1, x2 = c2 - f2, x3 = c3 - f3;
              // m = 2^-x, x in [0,1): quadratic through (0,1),(0.5,.70711),(1,0.5); err<0.2%
              float m0 = fmaf(x0, fmaf(x0, 0.17157f, -0.67157f), 1.0f);
              float m1 = fmaf(x1, fmaf(x1, 0.17157f, -0.67157f), 1.0f);
              float m2 = fmaf(x2, fmaf(x2, 0.17157f, -0.67157f), 1.0f);
              float m3 = fmaf(x3, fmaf(x3, 0.17157f, -0.67157f), 1.0f);
              int pkm = __builtin_amdgcn_cvt_pk_fp8_f32(m0, m1, 0, false);
              pkm = __builtin_amdgcn_cvt_pk_fp8_f32(m2, m3, pkm, true);
              unsigned int pkc = (unsigned int)f0 | ((unsigned int)f1 << 8)
                               | ((unsigned int)f2 << 16) | ((unsigned int)f3 << 24);
              const int t_row = 4 * Rt + hk;
              const int s1 = Ct * 16 + lr + t_row; // diagonal line index
              const int widx = (s1 & 31) * RSTR + t_row;
              ring0[widx] = (unsigned int)pkm;
              ring1[widx] = pkc;
            }
          }
          // ---- 4 DP steps: lines 4k..4k+3 complete ----
          unsigned int w0[4], w1[4];
          #pragma unroll
          for (int u = 0; u < 4; ++u) {
            const int s1 = 4 * k + u;
            const int ridx = (s1 & 31) * RSTR + t;
            w0[u] = ring0[ridx];
            w1[u] = ring1[ridx];
          }
          step(w0[0], w1[0]);
          step(w0[1], w1[1]);
          step(w0[2], w1[2]);
          step(w0[3], w1[3]);
        }
      }
    }
  }

  // ---- tail: lines 304..318 ----
  #pragma unroll
  for (int u = 0; u < 15; ++u) {
    const int s1 = 304 + u;
    const int ridx = (s1 & 31) * RSTR + t;
    step(ring0[ridx], ring1[ridx]);
  }

  // lane 63 holds V[256][256]: V = d - log2(E) (log2 domain)
  if (t == 63) atomicAdd(out, wgt * ((float)d4 - __log2f(E4)));
}

extern "C" void kernel_launch(void* const* d_in, const int* in_sizes, int n_in,
                              void* d_out, int out_size, void* d_ws, size_t ws_size,
                              hipStream_t stream) {
  const float* X = (const float*)d_in[0];
  const float* Y = (const float*)d_in[1];
  float* out = (float*)d_out;
  hipMemsetAsync(out, 0, sizeof(float) * out_size, stream);
  sdtw_fused3<<<1536, 64, 0, stream>>>(X, Y, out);
}